// Round 10
// baseline (328.249 us; speedup 1.0000x reference)
//
#include <hip/hip_runtime.h>
#include <stdint.h>

// RNN_autoreg: 2-layer LSTM (B=4096, T=60, H=128), one persistent kernel.
// 256 blocks (1/CU), 512 threads (8 waves), 16 batch rows/block.
// r10 = round-6 passing kernel + cross-barrier X-fragment register prefetch:
// X-frags (and xa) for the next body's x-part are ds_read at body end and kept
// in flight ACROSS the barrier via counted s_waitcnt lgkmcnt(5/4) (in-order DS
// retirement drains all earlier writes; sched_barrier(0) pins store->load
// order). Staging retimed 3-ahead (mod-4 ring: consume s+1 via regs,
// prefetch-read s+2, write s+3 - distinct mod 4).

typedef __bf16 bf16x8 __attribute__((ext_vector_type(8)));
typedef __bf16 bf16x4 __attribute__((ext_vector_type(4)));
typedef float  f32x4  __attribute__((ext_vector_type(4)));

#define HQ      4096u
#define H0_OFF  0u        // H dbuf: 2 x 4096
#define XD_OFF  8192u     // X ring: 4 x 4096 (slot = slice & 3)
#define XA_OFF  24576u    // x-input frags: [60][16] bf16x4 = 7680 B
#define HIST    32256u    // 32 slices x 4096 (slices 28..59 -> slot s-28)
#define LDS_SZ  163328
#define NWS     28        // slices 0..27 go through workspace

#define S1f (-1.4426950408889634f)   // -log2(e)   for i,f,o gates
#define S2f (-2.8853900817779268f)   // -2*log2(e) for g gate / tanh(c)

__device__ __forceinline__ bf16x8 ldw8s(const float* __restrict__ p, float s){
  float4 a = *(const float4*)p;
  float4 b = *(const float4*)(p+4);
  bf16x8 r;
  r[0]=(__bf16)(a.x*s); r[1]=(__bf16)(a.y*s); r[2]=(__bf16)(a.z*s); r[3]=(__bf16)(a.w*s);
  r[4]=(__bf16)(b.x*s); r[5]=(__bf16)(b.y*s); r[6]=(__bf16)(b.z*s); r[7]=(__bf16)(b.w*s);
  return r;
}
__device__ __forceinline__ void load_wgate(bf16x8 (&dst)[8], const float* pih, const float* phh, int gg, float s){
  #pragma unroll
  for (int kk=0;kk<4;++kk) dst[kk]   = ldw8s(pih + kk*32 + gg*8, s);
  #pragma unroll
  for (int kk=0;kk<4;++kk) dst[4+kk] = ldw8s(phh + kk*32 + gg*8, s);
}
// Barriers. BAR0: full LDS drain. BAR5/BAR4: leave exactly the N trailing
// prefetch ds_reads in flight (DS retires in order -> all earlier writes done).
#define BAR0() asm volatile("s_waitcnt lgkmcnt(0)\n\ts_barrier" ::: "memory")
#define BAR4() asm volatile("s_waitcnt lgkmcnt(4)\n\ts_barrier" ::: "memory")
#define BAR5() asm volatile("s_waitcnt lgkmcnt(5)\n\ts_barrier" ::: "memory")
__device__ __forceinline__ void step_barrier(){ BAR0(); }

// Pointwise with exp2-prescaled gates: a0=-L*i, a1=-L*f, a2=-2L*g, a3=-L*o.
__device__ __forceinline__ void lstm_pw(const f32x4& a0, const f32x4& a1,
                                        const f32x4& a2, const f32x4& a3,
                                        float (&c_)[4], float (&hn)[4]){
  #pragma unroll
  for (int i=0;i<4;++i){
    float ei = __builtin_amdgcn_exp2f(a0[i]);
    float ef = __builtin_amdgcn_exp2f(a1[i]);
    float eg = __builtin_amdgcn_exp2f(fminf(a2[i], 126.0f));  // clamp: lone NaN edge
    float eo = __builtin_amdgcn_exp2f(a3[i]);
    float sf = __builtin_amdgcn_rcpf(1.0f + ef);
    float itg = (1.0f - eg) * __builtin_amdgcn_rcpf((1.0f + ei)*(1.0f + eg));
    float ci = sf*c_[i] + itg;
    float ec = __builtin_amdgcn_exp2f(S2f*__builtin_fabsf(ci));
    float th = (1.0f - ec) * __builtin_amdgcn_rcpf((1.0f + eo)*(1.0f + ec));
    c_[i] = ci;
    hn[i] = __builtin_copysignf(th, ci);
  }
}

// Fold W_out @ W_lat -> wcomb[4][128], bcomb[4] at wcomb[512..515]
__global__ void comb_kernel(const float* __restrict__ W_lat, const float* __restrict__ b_lat,
                            const float* __restrict__ W_out, const float* __restrict__ b_out,
                            float* __restrict__ wcomb){
  int tid = threadIdx.x;
  int m = tid >> 7, k = tid & 127;
  float s = 0.f;
  for (int a=0;a<128;++a) s += W_out[m*128+a]*W_lat[a*128+k];
  wcomb[tid] = s;
  if (tid < 4){
    float sb = b_out[tid];
    for (int a=0;a<128;++a) sb += W_out[tid*128+a]*b_lat[a];
    wcomb[512+tid] = sb;
  }
}

#define MF(af_,wb_,ac_) ac_ = __builtin_amdgcn_mfma_f32_16x16x32_bf16(af_, wb_, ac_, 0,0,0)
#define BC8(q_) __builtin_bit_cast(bf16x8, q_)
// slice s lives at HIST (s>=28) or ring slot s&3
#define XSLOT(s_) (((s_) >= NWS) ? (HIST + (uint32_t)((s_)-NWS)*HQ) : (XD_OFF + (uint32_t)((s_)&3)*HQ))

// 4-frag prefetch into named registers
#define PF(X0_,X1_,X2_,X3_, SLOT_) { \
    X0_ = *(const uint4*)(lds + (SLOT_) + ((abase       ) ^ amask)); \
    X1_ = *(const uint4*)(lds + (SLOT_) + ((abase +  64u) ^ amask)); \
    X2_ = *(const uint4*)(lds + (SLOT_) + ((abase + 128u) ^ amask)); \
    X3_ = *(const uint4*)(lds + (SLOT_) + ((abase + 192u) ^ amask)); }

// Direct-read x-part (pre-loop priming only)
#define XPART1(A0_,A1_,A2_,A3_, XB_, TT_) do{ \
    bf16x8 xa_ = {}; \
    if (gg == 0){ bf16x4 x4_ = *(const bf16x4*)(lds + XA_OFF + (uint32_t)((((TT_))<<4)+l16)*8u); \
      xa_[0]=x4_[0]; xa_[1]=x4_[1]; xa_[2]=x4_[2]; xa_[3]=x4_[3]; } \
    A0_ = (f32x4){bias0,bias0,bias0,bias0}; \
    A1_ = (f32x4){bias1,bias1,bias1,bias1}; \
    A2_ = (f32x4){bias2,bias2,bias2,bias2}; \
    A3_ = (f32x4){bias3,bias3,bias3,bias3}; \
    MF(xa_,wxB0,A0_); MF(xa_,wxB1,A1_); MF(xa_,wxB2,A2_); MF(xa_,wxB3,A3_); \
    _Pragma("unroll") \
    for (int kk_=0;kk_<4;++kk_){ \
      uint4 q_ = *(const uint4*)(lds + (XB_) + ((abase + 64u*(uint32_t)kk_) ^ amask)); \
      bf16x8 af_ = BC8(q_); \
      MF(af_,wB0[kk_],A0_); MF(af_,wB1[kk_],A1_); MF(af_,wB2[kk_],A2_); MF(af_,wB3[kk_],A3_); } \
  }while(0)

#define XPART2(A0_,A1_,A2_,A3_, XB_) do{ \
    A0_ = (f32x4){bias0,bias0,bias0,bias0}; \
    A1_ = (f32x4){bias1,bias1,bias1,bias1}; \
    A2_ = (f32x4){bias2,bias2,bias2,bias2}; \
    A3_ = (f32x4){bias3,bias3,bias3,bias3}; \
    _Pragma("unroll") \
    for (int kk_=0;kk_<4;++kk_){ \
      uint4 q_ = *(const uint4*)(lds + (XB_) + ((abase + 64u*(uint32_t)kk_) ^ amask)); \
      bf16x8 af_ = BC8(q_); \
      MF(af_,wB0[kk_],A0_); MF(af_,wB1[kk_],A1_); MF(af_,wB2[kk_],A2_); MF(af_,wB3[kk_],A3_); } \
  }while(0)

// Register-operand x-part (steady state)
#define XPART1R(A0_,A1_,A2_,A3_, X0_,X1_,X2_,X3_, XAV_) do{ \
    bf16x8 xa_ = {}; \
    if (gg == 0){ xa_[0]=(XAV_)[0]; xa_[1]=(XAV_)[1]; xa_[2]=(XAV_)[2]; xa_[3]=(XAV_)[3]; } \
    A0_ = (f32x4){bias0,bias0,bias0,bias0}; \
    A1_ = (f32x4){bias1,bias1,bias1,bias1}; \
    A2_ = (f32x4){bias2,bias2,bias2,bias2}; \
    A3_ = (f32x4){bias3,bias3,bias3,bias3}; \
    MF(xa_,wxB0,A0_); MF(xa_,wxB1,A1_); MF(xa_,wxB2,A2_); MF(xa_,wxB3,A3_); \
    MF(BC8(X0_),wB0[0],A0_); MF(BC8(X0_),wB1[0],A1_); MF(BC8(X0_),wB2[0],A2_); MF(BC8(X0_),wB3[0],A3_); \
    MF(BC8(X1_),wB0[1],A0_); MF(BC8(X1_),wB1[1],A1_); MF(BC8(X1_),wB2[1],A2_); MF(BC8(X1_),wB3[1],A3_); \
    MF(BC8(X2_),wB0[2],A0_); MF(BC8(X2_),wB1[2],A1_); MF(BC8(X2_),wB2[2],A2_); MF(BC8(X2_),wB3[2],A3_); \
    MF(BC8(X3_),wB0[3],A0_); MF(BC8(X3_),wB1[3],A1_); MF(BC8(X3_),wB2[3],A2_); MF(BC8(X3_),wB3[3],A3_); \
  }while(0)

#define XPART2R(A0_,A1_,A2_,A3_, X0_,X1_,X2_,X3_) do{ \
    A0_ = (f32x4){bias0,bias0,bias0,bias0}; \
    A1_ = (f32x4){bias1,bias1,bias1,bias1}; \
    A2_ = (f32x4){bias2,bias2,bias2,bias2}; \
    A3_ = (f32x4){bias3,bias3,bias3,bias3}; \
    MF(BC8(X0_),wB0[0],A0_); MF(BC8(X0_),wB1[0],A1_); MF(BC8(X0_),wB2[0],A2_); MF(BC8(X0_),wB3[0],A3_); \
    MF(BC8(X1_),wB0[1],A0_); MF(BC8(X1_),wB1[1],A1_); MF(BC8(X1_),wB2[1],A2_); MF(BC8(X1_),wB3[1],A3_); \
    MF(BC8(X2_),wB0[2],A0_); MF(BC8(X2_),wB1[2],A1_); MF(BC8(X2_),wB2[2],A2_); MF(BC8(X2_),wB3[2],A3_); \
    MF(BC8(X3_),wB0[3],A0_); MF(BC8(X3_),wB1[3],A1_); MF(BC8(X3_),wB2[3],A2_); MF(BC8(X3_),wB3[3],A3_); \
  }while(0)

// Phase-1 body. C* already hold gates(T) x-part; N* filled with x-part(T+1)
// from the PREFETCHED register frags Xc (slice T+1, read end of body T-1).
// Staging 3-ahead: write slot T+3; prefetch-read slot T+2 at body end.
#define BODY1(T_, CUR_, C0,C1,C2,C3, N0,N1,N2,N3, Xc0,Xc1,Xc2,Xc3,xac, Xn0,Xn1,Xn2,Xn3,xan) { \
    const uint32_t Hc_ = H0_OFF + (uint32_t)(CUR_)*HQ; \
    uint4 qh0_ = *(const uint4*)(lds + Hc_ + ((abase       ) ^ amask)); \
    uint4 qh1_ = *(const uint4*)(lds + Hc_ + ((abase +  64u) ^ amask)); \
    uint4 qh2_ = *(const uint4*)(lds + Hc_ + ((abase + 128u) ^ amask)); \
    uint4 qh3_ = *(const uint4*)(lds + Hc_ + ((abase + 192u) ^ amask)); \
    uint2 hv_ = *(const uint2*)(lds + Hc_ + stg_off); \
    if ((T_) < 59) XPART1R(N0,N1,N2,N3, Xc0,Xc1,Xc2,Xc3, xac); \
    bf16x8 h0_ = BC8(qh0_), h1_ = BC8(qh1_), h2_ = BC8(qh2_), h3_ = BC8(qh3_); \
    MF(h0_,wB0[4],C0); MF(h0_,wB1[4],C1); MF(h0_,wB2[4],C2); MF(h0_,wB3[4],C3); \
    MF(h1_,wB0[5],C0); MF(h1_,wB1[5],C1); MF(h1_,wB2[5],C2); MF(h1_,wB3[5],C3); \
    MF(h2_,wB0[6],C0); MF(h2_,wB1[6],C1); MF(h2_,wB2[6],C2); MF(h2_,wB3[6],C3); \
    MF(h3_,wB0[7],C0); MF(h3_,wB1[7],C1); MF(h3_,wB2[7],C2); MF(h3_,wB3[7],C3); \
    float hn_[4]; \
    lstm_pw(C0,C1,C2,C3, c_, hn_); \
    if ((T_) >= 1){ \
      if ((T_) <= NWS) ws_u2[ws_base + (size_t)((T_)-1)*512 + tid] = hv_; \
      else *(uint2*)(lds + HIST + (uint32_t)((T_)-1-NWS)*HQ + stg_off) = hv_; \
    } \
    if ((T_) + 3 <= 59){ \
      const int s3_ = (T_) + 3; \
      const uint32_t sd_ = XSLOT(s3_); \
      bf16x4 m4_; m4_[0]=(__bf16)P0.x; m4_[1]=(__bf16)P0.y; m4_[2]=(__bf16)P0.z; m4_[3]=(__bf16)P0.w; \
      *(bf16x4*)(lds + sd_ + stg_off) = m4_; \
    } \
    _Pragma("unroll") \
    for (int i_=0;i_<4;++i_) \
      *(__bf16*)(lds + H0_OFF + (uint32_t)(1-(CUR_))*HQ + hw_off[i_]) = (__bf16)hn_[i_]; \
    P0 = P1; \
    if ((T_) + 5 <= 59) P1 = *(const float4*)(memrow + (size_t)((T_)+5)*128); \
    __builtin_amdgcn_sched_barrier(0); \
    if ((T_) <= 57){ \
      PF(Xn0,Xn1,Xn2,Xn3, XSLOT((T_)+2)); \
      xan = *(const bf16x4*)(lds + XA_OFF + (uint32_t)(((57-(T_))<<4)+l16)*8u); \
      __builtin_amdgcn_sched_barrier(0); \
      BAR5(); \
    } else { \
      __builtin_amdgcn_sched_barrier(0); \
      BAR0(); \
    } \
  }

// Phase-2 body (LSTM2 + fused out-MLP on wave 0). Consumes reg frags Xc
// (slice 58-T); prefetch-reads slice 57-T at body end. ws->ring staging
// unchanged (slice 56-T written at body T, prefetch-read at body 57-s).
#define BODY2(T_, CUR_, C0,C1,C2,C3, N0,N1,N2,N3, Xc0,Xc1,Xc2,Xc3, Xn0,Xn1,Xn2,Xn3) { \
    const uint32_t Hc_ = H0_OFF + (uint32_t)(CUR_)*HQ; \
    uint4 qh0_ = *(const uint4*)(lds + Hc_ + ((abase       ) ^ amask)); \
    uint4 qh1_ = *(const uint4*)(lds + Hc_ + ((abase +  64u) ^ amask)); \
    uint4 qh2_ = *(const uint4*)(lds + Hc_ + ((abase + 128u) ^ amask)); \
    uint4 qh3_ = *(const uint4*)(lds + Hc_ + ((abase + 192u) ^ amask)); \
    if ((T_) < 59) XPART2R(N0,N1,N2,N3, Xc0,Xc1,Xc2,Xc3); \
    bf16x8 h0_ = BC8(qh0_), h1_ = BC8(qh1_), h2_ = BC8(qh2_), h3_ = BC8(qh3_); \
    MF(h0_,wB0[4],C0); MF(h0_,wB1[4],C1); MF(h0_,wB2[4],C2); MF(h0_,wB3[4],C3); \
    MF(h1_,wB0[5],C0); MF(h1_,wB1[5],C1); MF(h1_,wB2[5],C2); MF(h1_,wB3[5],C3); \
    MF(h2_,wB0[6],C0); MF(h2_,wB1[6],C1); MF(h2_,wB2[6],C2); MF(h2_,wB3[6],C3); \
    MF(h3_,wB0[7],C0); MF(h3_,wB1[7],C1); MF(h3_,wB2[7],C2); MF(h3_,wB3[7],C3); \
    f32x4 ao_ = {0.f,0.f,0.f,0.f}; \
    if (w == 0){ MF(h0_,wcB[0],ao_); MF(h1_,wcB[1],ao_); MF(h2_,wcB[2],ao_); MF(h3_,wcB[3],ao_); } \
    float hn_[4]; \
    lstm_pw(C0,C1,C2,C3, c_, hn_); \
    if ((T_) > 0 && w == 0 && l16 < 4){ \
      _Pragma("unroll") \
      for (int i_=0;i_<4;++i_) \
        dout[(size_t)(b0 + gg*4 + i_)*240 + (size_t)((T_)-1)*4 + l16] = ao_[i_] + bc; \
    } \
    if ((T_) >= 29 && (T_) <= 56) \
      *(uint2*)(lds + XD_OFF + (uint32_t)((56-(T_))&3)*HQ + stg_off) = P0u; \
    _Pragma("unroll") \
    for (int i_=0;i_<4;++i_) \
      *(__bf16*)(lds + H0_OFF + (uint32_t)(1-(CUR_))*HQ + hw_off[i_]) = (__bf16)hn_[i_]; \
    P0u = P1u; \
    if ((T_) >= 27 && (T_) <= 54) P1u = ws_u2[ws_base + (size_t)(54-(T_))*512 + tid]; \
    __builtin_amdgcn_sched_barrier(0); \
    if ((T_) <= 57){ \
      PF(Xn0,Xn1,Xn2,Xn3, XSLOT(57-(T_))); \
      __builtin_amdgcn_sched_barrier(0); \
      BAR4(); \
    } else { \
      __builtin_amdgcn_sched_barrier(0); \
      BAR0(); \
    } \
  }

__global__ __launch_bounds__(512, 2)
void lstm_fused(const float* __restrict__ xmain_g, const float* __restrict__ sfc,
                const float* __restrict__ mem_g, const float* __restrict__ hx2g,
                const float* __restrict__ cx2g,
                const float* __restrict__ Wsfc1, const float* __restrict__ bsfc1,
                const float* __restrict__ Wsfc2, const float* __restrict__ bsfc2,
                const float* __restrict__ Wih1, const float* __restrict__ Whh1,
                const float* __restrict__ bih1, const float* __restrict__ bhh1,
                const float* __restrict__ Wih2, const float* __restrict__ Whh2,
                const float* __restrict__ bih2, const float* __restrict__ bhh2,
                const float* __restrict__ Wso, const float* __restrict__ bso,
                const float* __restrict__ wcomb_ws,
                uint2* __restrict__ ws_u2, float* __restrict__ dout)
{
  __shared__ __align__(16) unsigned char lds[LDS_SZ];
  const int tid = threadIdx.x;
  const int w   = tid >> 6;
  const int l   = tid & 63;
  const int gg  = l >> 4;
  const int l16 = l & 15;
  const int blk = blockIdx.x;
  const int b0  = blk * 16;
  const int j   = (w<<4) + l16;
  const uint32_t amask = (uint32_t)((l16 & 7) << 4);
  const uint32_t abase = (uint32_t)(l16*256 + gg*16);
  const int srow = tid >> 5;
  const uint32_t stg_off = (uint32_t)(((srow*256) + (tid&31)*8) ^ ((srow&7)<<4));
  uint32_t hw_off[4];
  #pragma unroll
  for (int i=0;i<4;++i){
    int r = gg*4 + i;
    hw_off[i] = (uint32_t)((r*256 + j*2) ^ ((r&7)<<4));
  }
  const size_t ws_base = (size_t)blk * NWS * 512;

  // ---------------- phase 1 prologue ----------------
  #pragma unroll
  for (int e = tid; e < 960; e += 512){      // XA: x inputs for all 60 steps
    int t = e >> 4, row = e & 15;
    float4 xv = *(const float4*)(xmain_g + (size_t)(b0+row)*240 + t*4);
    bf16x4 b4; b4[0]=(__bf16)xv.x; b4[1]=(__bf16)xv.y; b4[2]=(__bf16)xv.z; b4[3]=(__bf16)xv.w;
    *(bf16x4*)(lds + XA_OFF + (uint32_t)e*8u) = b4;
  }
  const float* memrow = mem_g + (size_t)(b0 + srow)*7680 + (tid&31)*4;
  { // ring slots 0,1,2 <- mem[:,0..2] (3-ahead staging discipline)
    float4 m0 = *(const float4*)memrow;
    float4 m1 = *(const float4*)(memrow + 128);
    float4 m2 = *(const float4*)(memrow + 256);
    bf16x4 a4; a4[0]=(__bf16)m0.x; a4[1]=(__bf16)m0.y; a4[2]=(__bf16)m0.z; a4[3]=(__bf16)m0.w;
    bf16x4 b4; b4[0]=(__bf16)m1.x; b4[1]=(__bf16)m1.y; b4[2]=(__bf16)m1.z; b4[3]=(__bf16)m1.w;
    bf16x4 c4; c4[0]=(__bf16)m2.x; c4[1]=(__bf16)m2.y; c4[2]=(__bf16)m2.z; c4[3]=(__bf16)m2.w;
    *(bf16x4*)(lds + XD_OFF + stg_off) = a4;
    *(bf16x4*)(lds + XD_OFF + HQ + stg_off) = b4;
    *(bf16x4*)(lds + XD_OFF + 2u*HQ + stg_off) = c4;
  }
  { // H[0] <- h1_0 = tanh(sfc @ Wsfc1^T + bsfc1)
    int c0 = (tid&31)*4;
    float4 wa = *(const float4*)(Wsfc1 + c0*3);
    float4 wb = *(const float4*)(Wsfc1 + c0*3 + 4);
    float4 wc = *(const float4*)(Wsfc1 + c0*3 + 8);
    const float* sp = sfc + (size_t)(b0+srow)*3;
    float s0 = sp[0], s1 = sp[1], s2 = sp[2];
    float4 bb = *(const float4*)(bsfc1 + c0);
    float v0 = tanhf(bb.x + s0*wa.x + s1*wa.y + s2*wa.z);
    float v1 = tanhf(bb.y + s0*wa.w + s1*wb.x + s2*wb.y);
    float v2 = tanhf(bb.z + s0*wb.z + s1*wb.w + s2*wc.x);
    float v3 = tanhf(bb.w + s0*wc.y + s1*wc.z + s2*wc.w);
    bf16x4 h4; h4[0]=(__bf16)v0; h4[1]=(__bf16)v1; h4[2]=(__bf16)v2; h4[3]=(__bf16)v3;
    *(bf16x4*)(lds + H0_OFF + stg_off) = h4;
  }
  float c_[4];
  {
    const float* wr = Wsfc2 + j*3;
    float w0_=wr[0], w1_=wr[1], w2_=wr[2];
    float bj = bsfc2[j];
    #pragma unroll
    for (int i=0;i<4;++i){
      const float* sp = sfc + (size_t)(b0 + gg*4 + i)*3;
      c_[i] = tanhf(bj + sp[0]*w0_ + sp[1]*w1_ + sp[2]*w2_);
    }
  }
  // weights, exp2-prescaled; K frags 0..3 = x-operand, 4..7 = h-operand
  bf16x8 wB0[8], wB1[8], wB2[8], wB3[8];
  load_wgate(wB0, Wih1 + 4 + (size_t)(0*128+j)*132, Whh1 + (size_t)(0*128+j)*128, gg, S1f);
  load_wgate(wB1, Wih1 + 4 + (size_t)(1*128+j)*132, Whh1 + (size_t)(1*128+j)*128, gg, S1f);
  load_wgate(wB2, Wih1 + 4 + (size_t)(2*128+j)*132, Whh1 + (size_t)(2*128+j)*128, gg, S2f);
  load_wgate(wB3, Wih1 + 4 + (size_t)(3*128+j)*132, Whh1 + (size_t)(3*128+j)*128, gg, S1f);
  bf16x8 wxB0 = {}, wxB1 = {}, wxB2 = {}, wxB3 = {};
  if (gg == 0){
    float4 x0 = *(const float4*)(Wih1 + (size_t)(0*128+j)*132);
    float4 x1 = *(const float4*)(Wih1 + (size_t)(1*128+j)*132);
    float4 x2 = *(const float4*)(Wih1 + (size_t)(2*128+j)*132);
    float4 x3 = *(const float4*)(Wih1 + (size_t)(3*128+j)*132);
    wxB0[0]=(__bf16)(x0.x*S1f); wxB0[1]=(__bf16)(x0.y*S1f); wxB0[2]=(__bf16)(x0.z*S1f); wxB0[3]=(__bf16)(x0.w*S1f);
    wxB1[0]=(__bf16)(x1.x*S1f); wxB1[1]=(__bf16)(x1.y*S1f); wxB1[2]=(__bf16)(x1.z*S1f); wxB1[3]=(__bf16)(x1.w*S1f);
    wxB2[0]=(__bf16)(x2.x*S2f); wxB2[1]=(__bf16)(x2.y*S2f); wxB2[2]=(__bf16)(x2.z*S2f); wxB2[3]=(__bf16)(x2.w*S2f);
    wxB3[0]=(__bf16)(x3.x*S1f); wxB3[1]=(__bf16)(x3.y*S1f); wxB3[2]=(__bf16)(x3.z*S1f); wxB3[3]=(__bf16)(x3.w*S1f);
  }
  float bias0 = (bih1[0*128+j] + bhh1[0*128+j])*S1f;
  float bias1 = (bih1[1*128+j] + bhh1[1*128+j])*S1f;
  float bias2 = (bih1[2*128+j] + bhh1[2*128+j])*S2f;
  float bias3 = (bih1[3*128+j] + bhh1[3*128+j])*S1f;
  float4 P0 = *(const float4*)(memrow + 3*128);   // mem[3] (staged at body 0)
  float4 P1 = *(const float4*)(memrow + 4*128);   // mem[4] (staged at body 1)
  step_barrier();

  f32x4 A0, A1, A2, A3, B0, B1, B2, B3;
  uint4 Fa0, Fa1, Fa2, Fa3, Fb0, Fb1, Fb2, Fb3;
  bf16x4 xaa, xab;
  XPART1(A0,A1,A2,A3, XD_OFF, 59);                 // gates(0) x-part (slot 0)
  PF(Fa0,Fa1,Fa2,Fa3, XD_OFF + HQ);                // prime: slice 1 frags
  xaa = *(const bf16x4*)(lds + XA_OFF + (uint32_t)((58<<4)+l16)*8u);

  // ---------------- phase 1: LSTM1 over flipped inputs ----------------
  #pragma unroll 1
  for (int tb = 0; tb < 60; tb += 2){
    BODY1(tb,   0, A0,A1,A2,A3, B0,B1,B2,B3, Fa0,Fa1,Fa2,Fa3,xaa, Fb0,Fb1,Fb2,Fb3,xab)
    BODY1(tb+1, 1, B0,B1,B2,B3, A0,A1,A2,A3, Fb0,Fb1,Fb2,Fb3,xab, Fa0,Fa1,Fa2,Fa3,xaa)
  }
  { // h1(59) (in H[0]) -> HIST slot 31; then H[0] <- hx2 (same-thread chunk, ordered)
    uint2 hv = *(const uint2*)(lds + H0_OFF + stg_off);
    *(uint2*)(lds + HIST + 31u*HQ + stg_off) = hv;
    float4 h2v = *(const float4*)(hx2g + (size_t)(b0+srow)*128 + (tid&31)*4);
    bf16x4 h4; h4[0]=(__bf16)h2v.x; h4[1]=(__bf16)h2v.y; h4[2]=(__bf16)h2v.z; h4[3]=(__bf16)h2v.w;
    *(bf16x4*)(lds + H0_OFF + stg_off) = h4;
  }
  #pragma unroll
  for (int i=0;i<4;++i) c_[i] = cx2g[(size_t)(b0 + gg*4 + i)*128 + j];
  load_wgate(wB0, Wih2 + (size_t)(0*128+j)*128, Whh2 + (size_t)(0*128+j)*128, gg, S1f);
  load_wgate(wB1, Wih2 + (size_t)(1*128+j)*128, Whh2 + (size_t)(1*128+j)*128, gg, S1f);
  load_wgate(wB2, Wih2 + (size_t)(2*128+j)*128, Whh2 + (size_t)(2*128+j)*128, gg, S2f);
  load_wgate(wB3, Wih2 + (size_t)(3*128+j)*128, Whh2 + (size_t)(3*128+j)*128, gg, S1f);
  {
    float nb0 = (bih2[0*128+j] + bhh2[0*128+j])*S1f;
    float nb1 = (bih2[1*128+j] + bhh2[1*128+j])*S1f;
    float nb2 = (bih2[2*128+j] + bhh2[2*128+j])*S2f;
    float nb3 = (bih2[3*128+j] + bhh2[3*128+j])*S1f;
    bias0=nb0; bias1=nb1; bias2=nb2; bias3=nb3;
  }
  bf16x8 wcB[4] = {};
  if (w == 0){
    #pragma unroll
    for (int kk=0;kk<4;++kk){
      bf16x8 v = {};
      if (l16 < 4) v = ldw8s(wcomb_ws + l16*128 + kk*32 + gg*8, 1.0f);
      wcB[kk] = v;
    }
  }
  const float bc = (l16 < 4) ? wcomb_ws[512 + l16] : 0.f;
  // drain ws hist stores before phase-2 reads; settle LDS
  asm volatile("s_waitcnt vmcnt(0) lgkmcnt(0)" ::: "memory");
  __builtin_amdgcn_s_barrier();

  uint2 P0u, P1u;
  XPART2(A0,A1,A2,A3, HIST + 31u*HQ);              // gates(0) x-part = slice 59
  PF(Fa0,Fa1,Fa2,Fa3, HIST + 30u*HQ);              // prime: slice 58 frags

  // ---------------- phase 2: LSTM2 + MFMA-fused output MLP ----------------
  #pragma unroll 1
  for (int tb = 0; tb < 60; tb += 2){
    BODY2(tb,   0, A0,A1,A2,A3, B0,B1,B2,B3, Fa0,Fa1,Fa2,Fa3, Fb0,Fb1,Fb2,Fb3)
    BODY2(tb+1, 1, B0,B1,B2,B3, A0,A1,A2,A3, Fb0,Fb1,Fb2,Fb3, Fa0,Fa1,Fa2,Fa3)
  }

  // ---------------- epilogue: out[59] + out_sfc from H[0] = h2(59) ----------------
  if (w == 0){
    bf16x8 wsB[4];
    #pragma unroll
    for (int kk=0;kk<4;++kk){
      bf16x8 v = {};
      if (l16 < 3) v = ldw8s(Wso + l16*128 + kk*32 + gg*8, 1.0f);
      wsB[kk] = v;
    }
    f32x4 ao = {0.f,0.f,0.f,0.f};
    f32x4 as_ = {0.f,0.f,0.f,0.f};
    #pragma unroll
    for (int kk=0;kk<4;++kk){
      uint4 q = *(const uint4*)(lds + H0_OFF + ((abase + 64u*(uint32_t)kk) ^ amask));
      bf16x8 af = BC8(q);
      ao  = __builtin_amdgcn_mfma_f32_16x16x32_bf16(af, wcB[kk], ao, 0,0,0);
      as_ = __builtin_amdgcn_mfma_f32_16x16x32_bf16(af, wsB[kk], as_, 0,0,0);
    }
    if (l16 < 4){
      #pragma unroll
      for (int i=0;i<4;++i)
        dout[(size_t)(b0 + gg*4 + i)*240 + 59*4 + l16] = ao[i] + bc;
    }
    if (l16 < 3){
      float bs = bso[l16];
      #pragma unroll
      for (int i=0;i<4;++i)
        dout[983040 + (size_t)(b0 + gg*4 + i)*3 + l16] = as_[i] + bs;
    }
  }
}

extern "C" void kernel_launch(void* const* d_in, const int* in_sizes, int n_in,
                              void* d_out, int out_size, void* d_ws, size_t ws_size,
                              hipStream_t stream){
  const float* inputs_main = (const float*)d_in[0];
  const float* inputs_sfc  = (const float*)d_in[1];
  const float* rnn1_mem    = (const float*)d_in[2];
  const float* hx2  = (const float*)d_in[3];
  const float* cx2  = (const float*)d_in[4];
  const float* W_sfc1 = (const float*)d_in[5];
  const float* b_sfc1 = (const float*)d_in[6];
  const float* W_sfc2 = (const float*)d_in[7];
  const float* b_sfc2 = (const float*)d_in[8];
  const float* Wih1 = (const float*)d_in[9];
  const float* Whh1 = (const float*)d_in[10];
  const float* bih1 = (const float*)d_in[11];
  const float* bhh1 = (const float*)d_in[12];
  const float* Wih2 = (const float*)d_in[13];
  const float* Whh2 = (const float*)d_in[14];
  const float* bih2 = (const float*)d_in[15];
  const float* bhh2 = (const float*)d_in[16];
  const float* W_lat = (const float*)d_in[17];
  const float* b_lat = (const float*)d_in[18];
  const float* W_out = (const float*)d_in[19];
  const float* b_out = (const float*)d_in[20];
  const float* W_so  = (const float*)d_in[21];
  const float* b_so  = (const float*)d_in[22];
  float* out = (float*)d_out;
  // ws: h1-history slices 0..27 (28 x 512 uint2 per block); wcomb at byte 62914560
  uint2* ws_u2 = (uint2*)d_ws;
  float* wcomb = (float*)((char*)d_ws + 62914560u);

  comb_kernel<<<dim3(1), dim3(512), 0, stream>>>(W_lat, b_lat, W_out, b_out, wcomb);
  lstm_fused<<<dim3(256), dim3(512), 0, stream>>>(inputs_main, inputs_sfc, rnn1_mem, hx2, cx2,
      W_sfc1, b_sfc1, W_sfc2, b_sfc2, Wih1, Whh1, bih1, bhh1, Wih2, Whh2, bih2, bhh2,
      W_so, b_so, wcomb, ws_u2, out);
}

// Round 11
// 194.225 us; speedup vs baseline: 1.6900x; 1.6900x over previous
//
#include <hip/hip_runtime.h>
#include <stdint.h>

// RNN_autoreg: 2-layer LSTM (B=4096, T=60, H=128), one persistent kernel.
// 256 blocks (1/CU), 512 threads (8 waves), 16 batch rows/block.
// RESTORED round-3 kernel (best measured: 194.2 us wall / 219.6 steady).
// h1-history LIFO in LDS (34 of 60 slices; slots double as phase-1 X staging),
// exp2-prescaled weights, out-MLP MFMA on wave 0 only, raw s_barrier
// (lgkmcnt-only wait), double-buffered H tiles, 1 barrier/step.
// Rounds 6-10 established: cross-step MFMA pipelining = neutral; reg-direct
// X from global = -19%; wave specialization = -47% (PART bank conflicts);
// counted-lgkm cross-barrier prefetch = -61% (sched_barrier pins). This
// structure is the measured optimum.

typedef __bf16 bf16x8 __attribute__((ext_vector_type(8)));
typedef __bf16 bf16x4 __attribute__((ext_vector_type(4)));
typedef float  f32x4  __attribute__((ext_vector_type(4)));

#define HQ      4096u
#define H0_OFF  0u        // H dbuf: 2 x 4096
#define XD_OFF  8192u     // X dbuf (early slots): 2 x 4096
#define XA_OFF  16384u    // x-input frags: [60][16] bf16x4 = 7680 B
#define HIST    24064u    // 34 slices x 4096 (slots 26..59)
#define LDS_SZ  163328
#define NWS     26        // slices 0..25 go through workspace

#define S1f (-1.4426950408889634f)   // -log2(e)   for i,f,o gates
#define S2f (-2.8853900817779268f)   // -2*log2(e) for g gate / tanh(c)

__device__ __forceinline__ bf16x8 ldw8s(const float* __restrict__ p, float s){
  float4 a = *(const float4*)p;
  float4 b = *(const float4*)(p+4);
  bf16x8 r;
  r[0]=(__bf16)(a.x*s); r[1]=(__bf16)(a.y*s); r[2]=(__bf16)(a.z*s); r[3]=(__bf16)(a.w*s);
  r[4]=(__bf16)(b.x*s); r[5]=(__bf16)(b.y*s); r[6]=(__bf16)(b.z*s); r[7]=(__bf16)(b.w*s);
  return r;
}
__device__ __forceinline__ void load_wgate(bf16x8 (&dst)[8], const float* pih, const float* phh, int gg, float s){
  #pragma unroll
  for (int kk=0;kk<4;++kk) dst[kk]   = ldw8s(pih + kk*32 + gg*8, s);
  #pragma unroll
  for (int kk=0;kk<4;++kk) dst[4+kk] = ldw8s(phh + kk*32 + gg*8, s);
}
// Raw barrier: LDS visibility only; register-destined global ops stay in flight.
__device__ __forceinline__ void step_barrier(){
  asm volatile("s_waitcnt lgkmcnt(0)\n\ts_barrier" ::: "memory");
}
// Pointwise with exp2-prescaled gates: a0=-L*i, a1=-L*f, a2=-2L*g, a3=-L*o.
__device__ __forceinline__ void lstm_pw(const f32x4& a0, const f32x4& a1,
                                        const f32x4& a2, const f32x4& a3,
                                        float (&c_)[4], float (&hn)[4]){
  #pragma unroll
  for (int i=0;i<4;++i){
    float ei = __builtin_amdgcn_exp2f(a0[i]);
    float ef = __builtin_amdgcn_exp2f(a1[i]);
    float eg = __builtin_amdgcn_exp2f(fminf(a2[i], 126.0f));  // clamp: lone NaN edge
    float eo = __builtin_amdgcn_exp2f(a3[i]);
    float sf = __builtin_amdgcn_rcpf(1.0f + ef);
    float itg = (1.0f - eg) * __builtin_amdgcn_rcpf((1.0f + ei)*(1.0f + eg));
    float ci = sf*c_[i] + itg;
    float ec = __builtin_amdgcn_exp2f(S2f*__builtin_fabsf(ci));
    float th = (1.0f - ec) * __builtin_amdgcn_rcpf((1.0f + eo)*(1.0f + ec));
    c_[i] = ci;
    hn[i] = __builtin_copysignf(th, ci);
  }
}

// Fold W_out @ W_lat -> wcomb[4][128], bcomb[4] at wcomb[512..515]
__global__ void comb_kernel(const float* __restrict__ W_lat, const float* __restrict__ b_lat,
                            const float* __restrict__ W_out, const float* __restrict__ b_out,
                            float* __restrict__ wcomb){
  int tid = threadIdx.x;
  int m = tid >> 7, k = tid & 127;
  float s = 0.f;
  for (int a=0;a<128;++a) s += W_out[m*128+a]*W_lat[a*128+k];
  wcomb[tid] = s;
  if (tid < 4){
    float sb = b_out[tid];
    for (int a=0;a<128;++a) sb += W_out[tid*128+a]*b_lat[a];
    wcomb[512+tid] = sb;
  }
}

#define MFMA4(BASE, K0) \
  { _Pragma("unroll") \
    for (int kk=0;kk<4;++kk){ \
      uint4 q = *(const uint4*)(lds + (BASE) + ((abase + 64u*(uint32_t)kk) ^ amask)); \
      bf16x8 af = __builtin_bit_cast(bf16x8, q); \
      a0 = __builtin_amdgcn_mfma_f32_16x16x32_bf16(af, wB0[kk+(K0)], a0, 0,0,0); \
      a1 = __builtin_amdgcn_mfma_f32_16x16x32_bf16(af, wB1[kk+(K0)], a1, 0,0,0); \
      a2 = __builtin_amdgcn_mfma_f32_16x16x32_bf16(af, wB2[kk+(K0)], a2, 0,0,0); \
      a3 = __builtin_amdgcn_mfma_f32_16x16x32_bf16(af, wB3[kk+(K0)], a3, 0,0,0); \
    } }

__global__ __launch_bounds__(512, 2)
void lstm_fused(const float* __restrict__ xmain_g, const float* __restrict__ sfc,
                const float* __restrict__ mem_g, const float* __restrict__ hx2g,
                const float* __restrict__ cx2g,
                const float* __restrict__ Wsfc1, const float* __restrict__ bsfc1,
                const float* __restrict__ Wsfc2, const float* __restrict__ bsfc2,
                const float* __restrict__ Wih1, const float* __restrict__ Whh1,
                const float* __restrict__ bih1, const float* __restrict__ bhh1,
                const float* __restrict__ Wih2, const float* __restrict__ Whh2,
                const float* __restrict__ bih2, const float* __restrict__ bhh2,
                const float* __restrict__ Wso, const float* __restrict__ bso,
                const float* __restrict__ wcomb_ws,
                uint2* __restrict__ ws_u2, float* __restrict__ dout)
{
  __shared__ __align__(16) unsigned char lds[LDS_SZ];
  const int tid = threadIdx.x;
  const int w   = tid >> 6;
  const int l   = tid & 63;
  const int gg  = l >> 4;
  const int l16 = l & 15;
  const int blk = blockIdx.x;
  const int b0  = blk * 16;
  const int j   = (w<<4) + l16;
  const uint32_t amask = (uint32_t)((l16 & 7) << 4);
  const uint32_t abase = (uint32_t)(l16*256 + gg*16);
  const int srow = tid >> 5;
  const uint32_t stg_off = (uint32_t)(((srow*256) + (tid&31)*8) ^ ((srow&7)<<4));
  uint32_t hw_off[4];
  #pragma unroll
  for (int i=0;i<4;++i){
    int r = gg*4 + i;
    hw_off[i] = (uint32_t)((r*256 + j*2) ^ ((r&7)<<4));
  }
  const size_t ws_base = (size_t)blk * NWS * 512;

  // ---------------- phase 1 prologue ----------------
  #pragma unroll
  for (int e = tid; e < 960; e += 512){      // XA: x inputs for all 60 steps
    int t = e >> 4, row = e & 15;
    float4 xv = *(const float4*)(xmain_g + (size_t)(b0+row)*240 + t*4);
    bf16x4 b4; b4[0]=(__bf16)xv.x; b4[1]=(__bf16)xv.y; b4[2]=(__bf16)xv.z; b4[3]=(__bf16)xv.w;
    *(bf16x4*)(lds + XA_OFF + (uint32_t)e*8u) = b4;
  }
  const float* memrow = mem_g + (size_t)(b0 + srow)*7680 + (tid&31)*4;
  { // slot 0 (mem[:,0]) -> XD[0]
    float4 mv = *(const float4*)memrow;
    bf16x4 m4; m4[0]=(__bf16)mv.x; m4[1]=(__bf16)mv.y; m4[2]=(__bf16)mv.z; m4[3]=(__bf16)mv.w;
    *(bf16x4*)(lds + XD_OFF + stg_off) = m4;
  }
  { // H[0] <- h1_0 = tanh(sfc @ Wsfc1^T + bsfc1)
    int c0 = (tid&31)*4;
    float4 wa = *(const float4*)(Wsfc1 + c0*3);
    float4 wb = *(const float4*)(Wsfc1 + c0*3 + 4);
    float4 wc = *(const float4*)(Wsfc1 + c0*3 + 8);
    const float* sp = sfc + (size_t)(b0+srow)*3;
    float s0 = sp[0], s1 = sp[1], s2 = sp[2];
    float4 bb = *(const float4*)(bsfc1 + c0);
    float v0 = tanhf(bb.x + s0*wa.x + s1*wa.y + s2*wa.z);
    float v1 = tanhf(bb.y + s0*wa.w + s1*wb.x + s2*wb.y);
    float v2 = tanhf(bb.z + s0*wb.z + s1*wb.w + s2*wc.x);
    float v3 = tanhf(bb.w + s0*wc.y + s1*wc.z + s2*wc.w);
    bf16x4 h4; h4[0]=(__bf16)v0; h4[1]=(__bf16)v1; h4[2]=(__bf16)v2; h4[3]=(__bf16)v3;
    *(bf16x4*)(lds + H0_OFF + stg_off) = h4;
  }
  float c_[4];
  {
    const float* wr = Wsfc2 + j*3;
    float w0_=wr[0], w1_=wr[1], w2_=wr[2];
    float bj = bsfc2[j];
    #pragma unroll
    for (int i=0;i<4;++i){
      const float* sp = sfc + (size_t)(b0 + gg*4 + i)*3;
      c_[i] = tanhf(bj + sp[0]*w0_ + sp[1]*w1_ + sp[2]*w2_);
    }
  }
  // weights, exp2-prescaled; K frags 0..3 = x-operand, 4..7 = h-operand
  bf16x8 wB0[8], wB1[8], wB2[8], wB3[8];
  load_wgate(wB0, Wih1 + 4 + (size_t)(0*128+j)*132, Whh1 + (size_t)(0*128+j)*128, gg, S1f);
  load_wgate(wB1, Wih1 + 4 + (size_t)(1*128+j)*132, Whh1 + (size_t)(1*128+j)*128, gg, S1f);
  load_wgate(wB2, Wih1 + 4 + (size_t)(2*128+j)*132, Whh1 + (size_t)(2*128+j)*128, gg, S2f);
  load_wgate(wB3, Wih1 + 4 + (size_t)(3*128+j)*132, Whh1 + (size_t)(3*128+j)*128, gg, S1f);
  bf16x8 wxB0 = {}, wxB1 = {}, wxB2 = {}, wxB3 = {};
  if (gg == 0){
    float4 x0 = *(const float4*)(Wih1 + (size_t)(0*128+j)*132);
    float4 x1 = *(const float4*)(Wih1 + (size_t)(1*128+j)*132);
    float4 x2 = *(const float4*)(Wih1 + (size_t)(2*128+j)*132);
    float4 x3 = *(const float4*)(Wih1 + (size_t)(3*128+j)*132);
    wxB0[0]=(__bf16)(x0.x*S1f); wxB0[1]=(__bf16)(x0.y*S1f); wxB0[2]=(__bf16)(x0.z*S1f); wxB0[3]=(__bf16)(x0.w*S1f);
    wxB1[0]=(__bf16)(x1.x*S1f); wxB1[1]=(__bf16)(x1.y*S1f); wxB1[2]=(__bf16)(x1.z*S1f); wxB1[3]=(__bf16)(x1.w*S1f);
    wxB2[0]=(__bf16)(x2.x*S2f); wxB2[1]=(__bf16)(x2.y*S2f); wxB2[2]=(__bf16)(x2.z*S2f); wxB2[3]=(__bf16)(x2.w*S2f);
    wxB3[0]=(__bf16)(x3.x*S1f); wxB3[1]=(__bf16)(x3.y*S1f); wxB3[2]=(__bf16)(x3.z*S1f); wxB3[3]=(__bf16)(x3.w*S1f);
  }
  float bias0 = (bih1[0*128+j] + bhh1[0*128+j])*S1f;
  float bias1 = (bih1[1*128+j] + bhh1[1*128+j])*S1f;
  float bias2 = (bih1[2*128+j] + bhh1[2*128+j])*S2f;
  float bias3 = (bih1[3*128+j] + bhh1[3*128+j])*S1f;
  float4 P0 = *(const float4*)(memrow + 128);   // prefetch mem[1]
  step_barrier();

  // ---------------- phase 1: LSTM1 over flipped inputs ----------------
  #pragma unroll 1
  for (int t=0; t<60; ++t){
    const uint32_t cur = (uint32_t)(t & 1), nxt = cur ^ 1u;
    const uint32_t Hc = H0_OFF + cur*HQ;
    const uint32_t xbase = (t >= NWS) ? (HIST + (uint32_t)(t-NWS)*HQ) : (XD_OFF + cur*HQ);
    float4 P1;
    if (t+2 < 60) P1 = *(const float4*)(memrow + (size_t)(t+2)*128);
    if (t > 0){   // h1(t-1): slots 0..25 -> ws, 26.. -> LDS hist
      uint2 hv = *(const uint2*)(lds + Hc + stg_off);
      if (t <= NWS) ws_u2[ws_base + (size_t)(t-1)*512 + tid] = hv;
      else *(uint2*)(lds + HIST + (uint32_t)(t-1-NWS)*HQ + stg_off) = hv;
    }
    const int tt = 59 - t;
    bf16x8 xa = {};
    if (gg == 0){
      bf16x4 x4 = *(const bf16x4*)(lds + XA_OFF + (uint32_t)((tt<<4) + l16)*8u);
      xa[0]=x4[0]; xa[1]=x4[1]; xa[2]=x4[2]; xa[3]=x4[3];
    }
    f32x4 a0 = {bias0,bias0,bias0,bias0};
    f32x4 a1 = {bias1,bias1,bias1,bias1};
    f32x4 a2 = {bias2,bias2,bias2,bias2};
    f32x4 a3 = {bias3,bias3,bias3,bias3};
    a0 = __builtin_amdgcn_mfma_f32_16x16x32_bf16(xa, wxB0, a0, 0,0,0);
    a1 = __builtin_amdgcn_mfma_f32_16x16x32_bf16(xa, wxB1, a1, 0,0,0);
    a2 = __builtin_amdgcn_mfma_f32_16x16x32_bf16(xa, wxB2, a2, 0,0,0);
    a3 = __builtin_amdgcn_mfma_f32_16x16x32_bf16(xa, wxB3, a3, 0,0,0);
    MFMA4(xbase, 0)
    MFMA4(Hc, 4)
    float hn[4];
    lstm_pw(a0, a1, a2, a3, c_, hn);
    if (t < 59){ // stage mem[t+1] into slot t+1
      const uint32_t sdst = (t+1 >= NWS) ? (HIST + (uint32_t)(t+1-NWS)*HQ) : (XD_OFF + nxt*HQ);
      bf16x4 m4; m4[0]=(__bf16)P0.x; m4[1]=(__bf16)P0.y; m4[2]=(__bf16)P0.z; m4[3]=(__bf16)P0.w;
      *(bf16x4*)(lds + sdst + stg_off) = m4;
    }
    #pragma unroll
    for (int i=0;i<4;++i)
      *(__bf16*)(lds + H0_OFF + nxt*HQ + hw_off[i]) = (__bf16)hn[i];
    P0 = P1;
    step_barrier();
  }
  { // h1(59) (in H[0]) -> HIST slot 33; then H[0] <- hx2 (same-thread chunk, ordered)
    uint2 hv = *(const uint2*)(lds + H0_OFF + stg_off);
    *(uint2*)(lds + HIST + 33u*HQ + stg_off) = hv;
    float4 h2v = *(const float4*)(hx2g + (size_t)(b0+srow)*128 + (tid&31)*4);
    bf16x4 h4; h4[0]=(__bf16)h2v.x; h4[1]=(__bf16)h2v.y; h4[2]=(__bf16)h2v.z; h4[3]=(__bf16)h2v.w;
    *(bf16x4*)(lds + H0_OFF + stg_off) = h4;
  }
  #pragma unroll
  for (int i=0;i<4;++i) c_[i] = cx2g[(size_t)(b0 + gg*4 + i)*128 + j];
  load_wgate(wB0, Wih2 + (size_t)(0*128+j)*128, Whh2 + (size_t)(0*128+j)*128, gg, S1f);
  load_wgate(wB1, Wih2 + (size_t)(1*128+j)*128, Whh2 + (size_t)(1*128+j)*128, gg, S1f);
  load_wgate(wB2, Wih2 + (size_t)(2*128+j)*128, Whh2 + (size_t)(2*128+j)*128, gg, S2f);
  load_wgate(wB3, Wih2 + (size_t)(3*128+j)*128, Whh2 + (size_t)(3*128+j)*128, gg, S1f);
  float nb0 = (bih2[0*128+j] + bhh2[0*128+j])*S1f;
  float nb1 = (bih2[1*128+j] + bhh2[1*128+j])*S1f;
  float nb2 = (bih2[2*128+j] + bhh2[2*128+j])*S2f;
  float nb3 = (bih2[3*128+j] + bhh2[3*128+j])*S1f;
  bias0=nb0; bias1=nb1; bias2=nb2; bias3=nb3;
  bf16x8 wcB[4] = {};
  if (w == 0){
    #pragma unroll
    for (int kk=0;kk<4;++kk){
      bf16x8 v = {};
      if (l16 < 4) v = ldw8s(wcomb_ws + l16*128 + kk*32 + gg*8, 1.0f);
      wcB[kk] = v;
    }
  }
  const float bc = (l16 < 4) ? wcomb_ws[512 + l16] : 0.f;
  // drain ws hist stores before phase-2 reads; settle LDS
  asm volatile("s_waitcnt vmcnt(0) lgkmcnt(0)" ::: "memory");
  __builtin_amdgcn_s_barrier();

  // ---------------- phase 2: LSTM2 + MFMA-fused output MLP ----------------
  uint2 P0u, P1u;
  #pragma unroll 1
  for (int t=0; t<60; ++t){
    const uint32_t cur = (uint32_t)(t & 1), nxt = cur ^ 1u;
    const uint32_t Hc = H0_OFF + cur*HQ;
    const int s = 59 - t;
    const uint32_t xbase = (s >= NWS) ? (HIST + (uint32_t)(s-NWS)*HQ) : (XD_OFF + cur*HQ);
    if (t >= 32 && t < 58) P1u = ws_u2[ws_base + (size_t)(57-t)*512 + tid];  // slice 57-t
    f32x4 a0 = {bias0,bias0,bias0,bias0};
    f32x4 a1 = {bias1,bias1,bias1,bias1};
    f32x4 a2 = {bias2,bias2,bias2,bias2};
    f32x4 a3 = {bias3,bias3,bias3,bias3};
    f32x4 ao = {0.f,0.f,0.f,0.f};
    MFMA4(xbase, 0)
    bf16x8 hf[4];
    #pragma unroll
    for (int kk=0;kk<4;++kk){
      uint4 q = *(const uint4*)(lds + Hc + ((abase + 64u*(uint32_t)kk) ^ amask));
      hf[kk] = __builtin_bit_cast(bf16x8, q);
    }
    #pragma unroll
    for (int kk=0;kk<4;++kk){
      a0 = __builtin_amdgcn_mfma_f32_16x16x32_bf16(hf[kk], wB0[kk+4], a0, 0,0,0);
      a1 = __builtin_amdgcn_mfma_f32_16x16x32_bf16(hf[kk], wB1[kk+4], a1, 0,0,0);
      a2 = __builtin_amdgcn_mfma_f32_16x16x32_bf16(hf[kk], wB2[kk+4], a2, 0,0,0);
      a3 = __builtin_amdgcn_mfma_f32_16x16x32_bf16(hf[kk], wB3[kk+4], a3, 0,0,0);
    }
    if (w == 0){
      #pragma unroll
      for (int kk=0;kk<4;++kk)
        ao = __builtin_amdgcn_mfma_f32_16x16x32_bf16(hf[kk], wcB[kk], ao, 0,0,0);
    }
    float hn[4];
    lstm_pw(a0, a1, a2, a3, c_, hn);
    if (t > 0 && w == 0 && l16 < 4){
      #pragma unroll
      for (int i=0;i<4;++i)
        dout[(size_t)(b0 + gg*4 + i)*240 + (size_t)(t-1)*4 + l16] = ao[i] + bc;
    }
    if (t >= 33 && t < 59)
      *(uint2*)(lds + XD_OFF + nxt*HQ + stg_off) = P0u;   // stage ws slice for t+1
    #pragma unroll
    for (int i=0;i<4;++i)
      *(__bf16*)(lds + H0_OFF + nxt*HQ + hw_off[i]) = (__bf16)hn[i];
    P0u = P1u;
    step_barrier();
  }

  // ---------------- epilogue: out[59] + out_sfc from H[0] = h2(59) ----------------
  if (w == 0){
    bf16x8 wsB[4];
    #pragma unroll
    for (int kk=0;kk<4;++kk){
      bf16x8 v = {};
      if (l16 < 3) v = ldw8s(Wso + l16*128 + kk*32 + gg*8, 1.0f);
      wsB[kk] = v;
    }
    f32x4 ao = {0.f,0.f,0.f,0.f};
    f32x4 as_ = {0.f,0.f,0.f,0.f};
    #pragma unroll
    for (int kk=0;kk<4;++kk){
      uint4 q = *(const uint4*)(lds + H0_OFF + ((abase + 64u*(uint32_t)kk) ^ amask));
      bf16x8 af = __builtin_bit_cast(bf16x8, q);
      ao  = __builtin_amdgcn_mfma_f32_16x16x32_bf16(af, wcB[kk], ao, 0,0,0);
      as_ = __builtin_amdgcn_mfma_f32_16x16x32_bf16(af, wsB[kk], as_, 0,0,0);
    }
    if (l16 < 4){
      #pragma unroll
      for (int i=0;i<4;++i)
        dout[(size_t)(b0 + gg*4 + i)*240 + 59*4 + l16] = ao[i] + bc;
    }
    if (l16 < 3){
      float bs = bso[l16];
      #pragma unroll
      for (int i=0;i<4;++i)
        dout[983040 + (size_t)(b0 + gg*4 + i)*3 + l16] = as_[i] + bs;
    }
  }
}

extern "C" void kernel_launch(void* const* d_in, const int* in_sizes, int n_in,
                              void* d_out, int out_size, void* d_ws, size_t ws_size,
                              hipStream_t stream){
  const float* inputs_main = (const float*)d_in[0];
  const float* inputs_sfc  = (const float*)d_in[1];
  const float* rnn1_mem    = (const float*)d_in[2];
  const float* hx2  = (const float*)d_in[3];
  const float* cx2  = (const float*)d_in[4];
  const float* W_sfc1 = (const float*)d_in[5];
  const float* b_sfc1 = (const float*)d_in[6];
  const float* W_sfc2 = (const float*)d_in[7];
  const float* b_sfc2 = (const float*)d_in[8];
  const float* Wih1 = (const float*)d_in[9];
  const float* Whh1 = (const float*)d_in[10];
  const float* bih1 = (const float*)d_in[11];
  const float* bhh1 = (const float*)d_in[12];
  const float* Wih2 = (const float*)d_in[13];
  const float* Whh2 = (const float*)d_in[14];
  const float* bih2 = (const float*)d_in[15];
  const float* bhh2 = (const float*)d_in[16];
  const float* W_lat = (const float*)d_in[17];
  const float* b_lat = (const float*)d_in[18];
  const float* W_out = (const float*)d_in[19];
  const float* b_out = (const float*)d_in[20];
  const float* W_so  = (const float*)d_in[21];
  const float* b_so  = (const float*)d_in[22];
  float* out = (float*)d_out;
  // ws: h1-history slices 0..25 (swizzled image chunks); wcomb at byte 62914560
  uint2* ws_u2 = (uint2*)d_ws;
  float* wcomb = (float*)((char*)d_ws + 62914560u);

  comb_kernel<<<dim3(1), dim3(512), 0, stream>>>(W_lat, b_lat, W_out, b_out, wcomb);
  lstm_fused<<<dim3(256), dim3(512), 0, stream>>>(inputs_main, inputs_sfc, rnn1_mem, hx2, cx2,
      W_sfc1, b_sfc1, W_sfc2, b_sfc2, Wih1, Whh1, bih1, bhh1, Wih2, Whh2, bih2, bhh2,
      W_so, b_so, wcomb, ws_u2, out);
}